// Round 1
// baseline (2822.792 us; speedup 1.0000x reference)
//
#include <hip/hip_runtime.h>

// Problem constants
#define NB   2048      // users / segments
#define NP   16384     // posts
#define LL   50        // tokens per post
#define DD   300       // embedding dim
#define NFT  100       // filters per conv
#define NWT  12        // total kernel slices (3+4+5)
#define TPAD 52        // padded time dim in LDS (16B-aligned float4 rows)
#define INFEAT 768
#define HID2 128

__device__ __forceinline__ int lower_bound_i(const int* __restrict__ a, int n, int v) {
    int lo = 0, hi = n;
    while (lo < hi) {
        int mid = (lo + hi) >> 1;
        if (a[mid] < v) lo = mid + 1; else hi = mid;
    }
    return lo;
}

// Transpose conv weights into [d][slice(12)][nf(100)] so conv-phase loads are
// coalesced across nf lanes. slices: 0-2 = conv3 k, 3-6 = conv4 k, 7-11 = conv5 k.
__global__ void prep_weights(const float* __restrict__ w3, const float* __restrict__ w4,
                             const float* __restrict__ w5, float* __restrict__ W_all) {
    int idx = blockIdx.x * blockDim.x + threadIdx.x;
    if (idx >= DD * NWT * NFT) return;
    int nf = idx % NFT;
    int r  = idx / NFT;
    int j  = r % NWT;
    int d  = r / NWT;
    float v;
    if (j < 3)      v = w3[(nf * DD + d) * 3 + j];
    else if (j < 7) v = w4[(nf * DD + d) * 4 + (j - 3)];
    else            v = w5[(nf * DD + d) * 5 + (j - 7)];
    W_all[idx] = v;
}

// One block per user: segment-mean gather -> LDS hist -> 3x conv + relu +
// maxpool -> rec GEMV -> out[b*64 + o]
__global__ __launch_bounds__(320, 1) void user_kernel(
    const int* __restrict__ hist_tokens, const int* __restrict__ seg,
    const float* __restrict__ emb, const float* __restrict__ W_all,
    const float* __restrict__ b3, const float* __restrict__ b4, const float* __restrict__ b5,
    const float* __restrict__ hist_w, const float* __restrict__ hist_b,
    float* __restrict__ out)
{
    __shared__ __align__(16) float hist[DD * TPAD];   // [d][t] , 62400 B
    __shared__ __align__(16) float fpool[3 * NFT];    // pooled features, concat order
    __shared__ int tok[LL];

    const int b = blockIdx.x;
    const int tid = threadIdx.x;

    // segment range (segment_ids sorted ascending)
    const int lo  = lower_bound_i(seg, NP, b);
    const int hi  = lower_bound_i(seg, NP, b + 1);
    const int cnt = hi - lo;
    const float inv = 1.0f / fmaxf((float)cnt, 1.0f);

    // zero LDS hist (incl. t=50,51 pad so pad never injects NaN)
    for (int i = tid; i < DD * TPAD; i += 320) hist[i] = 0.0f;
    __syncthreads();

    // ---- phase B: segment sum in registers ----
    // element i = tid + 320*j over [0, 15000), i = t*300 + d (coalesced in d)
    float acc[47];
    #pragma unroll
    for (int j = 0; j < 47; ++j) acc[j] = 0.0f;

    const int t0 = tid / DD;           // 0 or 1
    const int d0 = tid - t0 * DD;

    for (int p = lo; p < hi; ++p) {
        if (tid < LL) tok[tid] = hist_tokens[p * LL + tid];
        __syncthreads();
        int t = t0, d = d0;
        #pragma unroll
        for (int j = 0; j < 47; ++j) {
            if (t < LL) acc[j] += emb[(long)tok[t] * DD + d];
            // i += 320  ==  t += 1, d += 20 (with carry)
            d += 20; t += 1; if (d >= DD) { d -= DD; t += 1; }
        }
        __syncthreads();
    }

    // write mean into LDS as [d][t]
    {
        int t = t0, d = d0;
        #pragma unroll
        for (int j = 0; j < 47; ++j) {
            if (t < LL) hist[d * TPAD + t] = acc[j] * inv;
            d += 20; t += 1; if (d >= DD) { d -= DD; t += 1; }
        }
    }
    __syncthreads();

    // ---- phase C: conv + relu + maxpool ----
    if (tid < 3 * NFT) {
        const int c  = tid / NFT;          // 0:K=3, 1:K=4, 2:K=5
        const int nf = tid - c * NFT;
        const int K  = c + 3;
        const int s0 = (c == 0) ? 0 : (c == 1) ? 3 : 7;
        const float bias = (c == 0 ? b3 : (c == 1 ? b4 : b5))[nf];
        const int Tout = LL - K + 1;       // 48 / 47 / 46

        float acc2[48];
        #pragma unroll
        for (int t = 0; t < 48; ++t) acc2[t] = 0.0f;

        const float* wb = W_all + s0 * NFT + nf;
        for (int d = 0; d < DD; ++d) {
            float w[5];
            #pragma unroll
            for (int k = 0; k < 5; ++k)
                w[k] = (k < K) ? wb[d * (NWT * NFT) + k * NFT] : 0.0f;

            float hv[52];
            const float4* hrow = (const float4*)(hist + d * TPAD);
            #pragma unroll
            for (int q = 0; q < 13; ++q) {
                float4 v = hrow[q];
                hv[4*q+0] = v.x; hv[4*q+1] = v.y; hv[4*q+2] = v.z; hv[4*q+3] = v.w;
            }
            #pragma unroll
            for (int t = 0; t < 48; ++t) {
                #pragma unroll
                for (int k = 0; k < 5; ++k)
                    acc2[t] += hv[t + k] * w[k];
            }
        }
        float m = acc2[0];
        for (int t = 1; t < Tout; ++t) m = fmaxf(m, acc2[t]);
        fpool[tid] = fmaxf(0.0f, m + bias);   // relu then max == max(0, max+bias)
    }
    __syncthreads();

    // ---- rec = fpool @ hist_w.T + hist_b ----
    if (tid < 64) {
        const float4* fw = (const float4*)(hist_w + tid * (3 * NFT));
        const float4* fp = (const float4*)fpool;
        float s = 0.0f;
        #pragma unroll
        for (int q = 0; q < 75; ++q) {
            float4 a = fp[q], w = fw[q];
            s += a.x*w.x + a.y*w.y + a.z*w.z + a.w*w.w;
        }
        out[b * 64 + tid] = s + hist_b[tid];
    }
}

// out[b] += relu(x[root[b]] @ fc_w1.T + fc_b1) @ fc_w2.T + fc_b2
__global__ __launch_bounds__(128, 1) void fc_kernel(
    const float* __restrict__ x, const int* __restrict__ rootindex,
    const float* __restrict__ w1, const float* __restrict__ b1,
    const float* __restrict__ w2, const float* __restrict__ b2,
    float* __restrict__ out)
{
    __shared__ __align__(16) float xr[INFEAT];
    __shared__ float h[HID2];
    const int b = blockIdx.x, tid = threadIdx.x;
    const int root = rootindex[b];

    const float4* xs = (const float4*)(x + (long)root * INFEAT);
    float4* xd = (float4*)xr;
    for (int i = tid; i < INFEAT / 4; i += 128) xd[i] = xs[i];
    __syncthreads();

    const float4* wr = (const float4*)(w1 + tid * INFEAT);
    const float4* xv = (const float4*)xr;
    float s = 0.0f;
    #pragma unroll 8
    for (int q = 0; q < INFEAT / 4; ++q) {
        float4 a = xv[q], w = wr[q];
        s += a.x*w.x + a.y*w.y + a.z*w.z + a.w*w.w;
    }
    h[tid] = fmaxf(s + b1[tid], 0.0f);
    __syncthreads();

    if (tid < 64) {
        const float* w2r = w2 + tid * HID2;
        float s2 = 0.0f;
        #pragma unroll
        for (int i = 0; i < HID2; ++i) s2 += h[i] * w2r[i];
        out[b * 64 + tid] += s2 + b2[tid];
    }
}

extern "C" void kernel_launch(void* const* d_in, const int* in_sizes, int n_in,
                              void* d_out, int out_size, void* d_ws, size_t ws_size,
                              hipStream_t stream) {
    const float* x        = (const float*)d_in[0];
    const int*   rootidx  = (const int*)d_in[1];
    const int*   hist_tok = (const int*)d_in[2];
    const int*   seg      = (const int*)d_in[3];
    const float* emb      = (const float*)d_in[4];
    const float* w3       = (const float*)d_in[5];
    const float* cb3      = (const float*)d_in[6];
    const float* w4       = (const float*)d_in[7];
    const float* cb4      = (const float*)d_in[8];
    const float* w5       = (const float*)d_in[9];
    const float* cb5      = (const float*)d_in[10];
    const float* hist_w   = (const float*)d_in[11];
    const float* hist_b   = (const float*)d_in[12];
    const float* fw1      = (const float*)d_in[13];
    const float* fb1      = (const float*)d_in[14];
    const float* fw2      = (const float*)d_in[15];
    const float* fb2      = (const float*)d_in[16];
    float* out   = (float*)d_out;
    float* W_all = (float*)d_ws;   // 360000 floats = 1.44 MB scratch

    prep_weights<<<(DD * NWT * NFT + 255) / 256, 256, 0, stream>>>(w3, w4, w5, W_all);
    user_kernel<<<NB, 320, 0, stream>>>(hist_tok, seg, emb, W_all, cb3, cb4, cb5,
                                        hist_w, hist_b, out);
    fc_kernel<<<NB, 128, 0, stream>>>(x, rootidx, fw1, fb1, fw2, fb2, out);
}

// Round 2
// 794.904 us; speedup vs baseline: 3.5511x; 3.5511x over previous
//
#include <hip/hip_runtime.h>

// Problem constants
#define NB    2048     // users / segments
#define NP    16384    // posts
#define LL    50       // tokens per post
#define DD    300      // embedding dim
#define DP    320      // d padded to multiple of 32 (MFMA K tiles)
#define TP    52       // t rows incl. zero pad (48 outputs + 4 shift overhang)
#define NTOT  300      // total filters (100 per conv)
#define NPADF 320      // filters padded to 20 N-tiles of 16
#define LDP   328      // LDS row stride in bf16 elems (656 B -> 2-way free banks)
#define INFEAT 768
#define HID2  128

typedef short v8s __attribute__((ext_vector_type(8)));
typedef float v4f __attribute__((ext_vector_type(4)));

__device__ __forceinline__ unsigned short f2bf(float f) {
    union { float f; unsigned u; } v; v.f = f;
    return (unsigned short)((v.u + 0x7FFF + ((v.u >> 16) & 1)) >> 16);  // RNE
}
__device__ __forceinline__ float bf2f(unsigned short u) {
    union { unsigned u; float f; } v; v.u = ((unsigned)u) << 16; return v.f;
}
__device__ __forceinline__ int lower_bound_i(const int* __restrict__ a, int n, int v) {
    int lo = 0, hi = n;
    while (lo < hi) { int mid = (lo + hi) >> 1; if (a[mid] < v) lo = mid + 1; else hi = mid; }
    return lo;
}

// ---- emb table fp32 -> bf16 (halves gather traffic) ----
__global__ void emb_cvt(const float* __restrict__ in, unsigned short* __restrict__ out, int n4) {
    int i = blockIdx.x * blockDim.x + threadIdx.x;
    if (i >= n4) return;
    float4 v = ((const float4*)in)[i];
    ushort4 o; o.x = f2bf(v.x); o.y = f2bf(v.y); o.z = f2bf(v.z); o.w = f2bf(v.w);
    ((ushort4*)out)[i] = o;
}

// ---- conv weights -> bf16 W5[shift(5)][nf(320)][d(320)] + bias_all[320] ----
__global__ void prep_w(const float* __restrict__ w3, const float* __restrict__ w4,
                       const float* __restrict__ w5,
                       const float* __restrict__ b3, const float* __restrict__ b4,
                       const float* __restrict__ b5,
                       unsigned short* __restrict__ W5, float* __restrict__ bias_all) {
    int idx = blockIdx.x * blockDim.x + threadIdx.x;
    if (idx < NPADF) {
        float bv = 0.f;
        if (idx < 100) bv = b3[idx];
        else if (idx < 200) bv = b4[idx - 100];
        else if (idx < 300) bv = b5[idx - 200];
        bias_all[idx] = bv;
    }
    if (idx >= 5 * NPADF * DP) return;
    int d  = idx % DP;
    int r  = idx / DP;
    int nf = r % NPADF;
    int s  = r / NPADF;
    float v = 0.f;
    if (nf < NTOT && d < DD) {
        int cls = nf / 100, f = nf % 100, K = cls + 3;
        if (s < K) {
            const float* w = (cls == 0) ? w3 : (cls == 1) ? w4 : w5;
            v = w[(f * DD + d) * K + s];
        }
    }
    W5[idx] = f2bf(v);
}

// ---- ragged segment-mean -> bf16 hist[b][52][320] (zero pad t>=50, d>=300) ----
__global__ __launch_bounds__(512, 1) void gather_kernel(
    const int* __restrict__ hist_tokens, const int* __restrict__ seg,
    const unsigned short* __restrict__ embb, unsigned short* __restrict__ histb)
{
    __shared__ int tok[16 * LL];
    const int b = blockIdx.x, tid = threadIdx.x;
    const int lo = lower_bound_i(seg, NP, b);
    const int hi = lower_bound_i(seg, NP, b + 1);
    const float inv = 1.0f / fmaxf((float)(hi - lo), 1.0f);

    float acc[31];
    #pragma unroll
    for (int j = 0; j < 31; ++j) acc[j] = 0.f;
    const int t0 = tid / DD;          // 0 or 1
    const int d0 = tid - t0 * DD;

    for (int p0 = lo; p0 < hi; p0 += 16) {
        const int pc = min(16, hi - p0);
        __syncthreads();
        for (int j = tid; j < pc * LL; j += 512)
            tok[j] = hist_tokens[(p0 + j / LL) * LL + (j % LL)];
        __syncthreads();
        for (int pp = 0; pp < pc; ++pp) {
            const int* tk = tok + pp * LL;
            int t = t0, d = d0;
            #pragma unroll
            for (int j = 0; j < 31; ++j) {
                if (t < LL) acc[j] += bf2f(embb[tk[t] * DD + d]);
                // i += 512 : t += 1, d += 212 (with carry)
                d += 212; t += 1; if (d >= DD) { d -= DD; t += 1; }
            }
        }
    }

    unsigned short* hb = histb + (size_t)b * TP * DP;
    {
        int t = t0, d = d0;
        #pragma unroll
        for (int j = 0; j < 31; ++j) {
            if (t < TP) hb[t * DP + d] = f2bf(t < LL ? acc[j] * inv : 0.f);
            d += 212; t += 1; if (d >= DD) { d -= DD; t += 1; }
        }
    }
    for (int idx = tid; idx < TP * (DP - DD); idx += 512) {
        int t = idx / (DP - DD), d = DD + idx % (DP - DD);
        hb[t * DP + d] = 0;
    }
}

// ---- per-user conv as 5 shifted MFMA GEMMs + maxpool + relu + rec GEMV ----
__global__ __launch_bounds__(320, 1) void conv_kernel(
    const unsigned short* __restrict__ histb, const unsigned short* __restrict__ W5,
    const float* __restrict__ bias_all,
    const float* __restrict__ hist_w, const float* __restrict__ hist_b,
    float* __restrict__ out)
{
    __shared__ __align__(16) unsigned short hl[TP * LDP];  // 34112 B
    __shared__ __align__(16) float fpool[NPADF];
    const int b = blockIdx.x, tid = threadIdx.x;
    const unsigned short* hb = histb + (size_t)b * TP * DP;

    // stage hist tile into LDS with padded stride (16B chunks)
    for (int c = tid; c < TP * (DP / 8); c += 320) {
        int t = c / (DP / 8), dd = (c % (DP / 8)) * 8;
        *(v8s*)(hl + t * LDP + dd) = *(const v8s*)(hb + t * DP + dd);
    }
    __syncthreads();

    const int wave = tid >> 6, lane = tid & 63;
    const int col = lane & 15, quad = lane >> 4;

    v4f acc[3][4];
    #pragma unroll
    for (int m = 0; m < 3; ++m)
        #pragma unroll
        for (int n = 0; n < 4; ++n)
            acc[m][n] = (v4f){0.f, 0.f, 0.f, 0.f};

    for (int s = 0; s < 5; ++s) {
        #pragma unroll
        for (int kt = 0; kt < 10; ++kt) {
            v8s a[3];
            #pragma unroll
            for (int m = 0; m < 3; ++m)
                a[m] = *(const v8s*)(hl + (m * 16 + col + s) * LDP + kt * 32 + quad * 8);
            #pragma unroll
            for (int n = 0; n < 4; ++n) {
                const v8s bf = *(const v8s*)(W5 +
                    ((size_t)((s * NPADF + (wave * 4 + n) * 16 + col)) * DP + kt * 32 + quad * 8));
                #pragma unroll
                for (int m = 0; m < 3; ++m)
                    acc[m][n] = __builtin_amdgcn_mfma_f32_16x16x32_bf16(a[m], bf, acc[m][n], 0, 0, 0);
            }
        }
    }

    // masked maxpool over t, cross-lane reduce, bias+relu
    #pragma unroll
    for (int n = 0; n < 4; ++n) {
        const int nf = (wave * 4 + n) * 16 + col;
        const int Tout = 48 - nf / 100;        // 48 / 47 / 46 (nf>=300 unused)
        float mx = -1e30f;
        #pragma unroll
        for (int m = 0; m < 3; ++m)
            #pragma unroll
            for (int r = 0; r < 4; ++r) {
                int t = m * 16 + quad * 4 + r;
                if (t < Tout) mx = fmaxf(mx, acc[m][n][r]);
            }
        mx = fmaxf(mx, __shfl_xor(mx, 16, 64));
        mx = fmaxf(mx, __shfl_xor(mx, 32, 64));
        if (quad == 0 && nf < NTOT)
            fpool[nf] = fmaxf(0.f, mx + bias_all[nf]);
    }
    __syncthreads();

    // rec = fpool @ hist_w.T + hist_b
    if (tid < 64) {
        const float4* fw = (const float4*)(hist_w + tid * NTOT);
        const float4* fp = (const float4*)fpool;
        float s = 0.f;
        #pragma unroll
        for (int q = 0; q < NTOT / 4; ++q) {
            float4 aa = fp[q], ww = fw[q];
            s += aa.x * ww.x + aa.y * ww.y + aa.z * ww.z + aa.w * ww.w;
        }
        out[b * 64 + tid] = s + hist_b[tid];
    }
}

// ---- out[b] += relu(x[root[b]] @ fc_w1.T + fc_b1) @ fc_w2.T + fc_b2 ----
__global__ __launch_bounds__(128, 1) void fc_kernel(
    const float* __restrict__ x, const int* __restrict__ rootindex,
    const float* __restrict__ w1, const float* __restrict__ b1,
    const float* __restrict__ w2, const float* __restrict__ b2,
    float* __restrict__ out)
{
    __shared__ __align__(16) float xr[INFEAT];
    __shared__ float h[HID2];
    const int b = blockIdx.x, tid = threadIdx.x;
    const int root = rootindex[b];

    const float4* xs = (const float4*)(x + (long)root * INFEAT);
    float4* xd = (float4*)xr;
    for (int i = tid; i < INFEAT / 4; i += 128) xd[i] = xs[i];
    __syncthreads();

    const float4* wr = (const float4*)(w1 + tid * INFEAT);
    const float4* xv = (const float4*)xr;
    float s = 0.f;
    #pragma unroll 8
    for (int q = 0; q < INFEAT / 4; ++q) {
        float4 a = xv[q], w = wr[q];
        s += a.x * w.x + a.y * w.y + a.z * w.z + a.w * w.w;
    }
    h[tid] = fmaxf(s + b1[tid], 0.f);
    __syncthreads();

    if (tid < 64) {
        const float* w2r = w2 + tid * HID2;
        float s2 = 0.f;
        #pragma unroll
        for (int i = 0; i < HID2; ++i) s2 += h[i] * w2r[i];
        out[b * 64 + tid] += s2 + b2[tid];
    }
}

extern "C" void kernel_launch(void* const* d_in, const int* in_sizes, int n_in,
                              void* d_out, int out_size, void* d_ws, size_t ws_size,
                              hipStream_t stream) {
    const float* x        = (const float*)d_in[0];
    const int*   rootidx  = (const int*)d_in[1];
    const int*   hist_tok = (const int*)d_in[2];
    const int*   seg      = (const int*)d_in[3];
    const float* emb      = (const float*)d_in[4];
    const float* w3       = (const float*)d_in[5];
    const float* cb3      = (const float*)d_in[6];
    const float* w4       = (const float*)d_in[7];
    const float* cb4      = (const float*)d_in[8];
    const float* w5       = (const float*)d_in[9];
    const float* cb5      = (const float*)d_in[10];
    const float* hist_w   = (const float*)d_in[11];
    const float* hist_b   = (const float*)d_in[12];
    const float* fw1      = (const float*)d_in[13];
    const float* fb1      = (const float*)d_in[14];
    const float* fw2      = (const float*)d_in[15];
    const float* fb2      = (const float*)d_in[16];
    float* out = (float*)d_out;

    // workspace layout (bytes)
    char* ws = (char*)d_ws;
    unsigned short* emb_bf  = (unsigned short*)(ws);                    // 30,000,000 B
    unsigned short* hist_bf = (unsigned short*)(ws + 30000000);         // 68,157,440 B
    unsigned short* W5      = (unsigned short*)(ws + 98157440);         //  1,024,000 B
    float*          bias_all= (float*)(ws + 99181440);                  //      1,280 B

    emb_cvt<<<(50000 * DD / 4 + 255) / 256, 256, 0, stream>>>(emb, emb_bf, 50000 * DD / 4);
    prep_w<<<(5 * NPADF * DP + 255) / 256, 256, 0, stream>>>(w3, w4, w5, cb3, cb4, cb5, W5, bias_all);
    gather_kernel<<<NB, 512, 0, stream>>>(hist_tok, seg, emb_bf, hist_bf);
    conv_kernel<<<NB, 320, 0, stream>>>(hist_bf, W5, bias_all, hist_w, hist_b, out);
    fc_kernel<<<NB, 128, 0, stream>>>(x, rootidx, fw1, fb1, fw2, fb2, out);
}

// Round 3
// 575.520 us; speedup vs baseline: 4.9048x; 1.3812x over previous
//
#include <hip/hip_runtime.h>

// Problem constants
#define NB    2048     // users / segments
#define NP    16384    // posts
#define LL    50       // tokens per post
#define DD    300      // embedding dim
#define DP    320      // d padded to multiple of 32 (MFMA K tiles)
#define TP    52       // t rows incl. zero pad (48 outputs + 4 shift overhang)
#define NTOT  300      // total filters (100 per conv)
#define NPADF 320      // filters padded to 20 N-tiles of 16
#define INFEAT 768
#define HID2  128
#define UPB   4        // users per conv block

typedef short v8s __attribute__((ext_vector_type(8)));
typedef float v4f __attribute__((ext_vector_type(4)));

__device__ __forceinline__ unsigned short f2bf(float f) {
    union { float f; unsigned u; } v; v.f = f;
    return (unsigned short)((v.u + 0x7FFF + ((v.u >> 16) & 1)) >> 16);  // RNE
}
__device__ __forceinline__ float bf2f(unsigned short u) {
    union { unsigned u; float f; } v; v.u = ((unsigned)u) << 16; return v.f;
}
__device__ __forceinline__ int lower_bound_i(const int* __restrict__ a, int n, int v) {
    int lo = 0, hi = n;
    while (lo < hi) { int mid = (lo + hi) >> 1; if (a[mid] < v) lo = mid + 1; else hi = mid; }
    return lo;
}

// ---- emb table fp32 -> bf16 ----
__global__ void emb_cvt(const float* __restrict__ in, unsigned short* __restrict__ out, int n4) {
    int i = blockIdx.x * blockDim.x + threadIdx.x;
    if (i >= n4) return;
    float4 v = ((const float4*)in)[i];
    ushort4 o; o.x = f2bf(v.x); o.y = f2bf(v.y); o.z = f2bf(v.z); o.w = f2bf(v.w);
    ((ushort4*)out)[i] = o;
}

// ---- conv weights -> bf16 W5[shift(5)][nf(320)][d(320)] + bias_all[320] ----
__global__ void prep_w(const float* __restrict__ w3, const float* __restrict__ w4,
                       const float* __restrict__ w5,
                       const float* __restrict__ b3, const float* __restrict__ b4,
                       const float* __restrict__ b5,
                       unsigned short* __restrict__ W5, float* __restrict__ bias_all) {
    int idx = blockIdx.x * blockDim.x + threadIdx.x;
    if (idx < NPADF) {
        float bv = 0.f;
        if (idx < 100) bv = b3[idx];
        else if (idx < 200) bv = b4[idx - 100];
        else if (idx < 300) bv = b5[idx - 200];
        bias_all[idx] = bv;
    }
    if (idx >= 5 * NPADF * DP) return;
    int d  = idx % DP;
    int r  = idx / DP;
    int nf = r % NPADF;
    int s  = r / NPADF;
    float v = 0.f;
    if (nf < NTOT && d < DD) {
        int cls = nf / 100, f = nf % 100, K = cls + 3;
        if (s < K) {
            const float* w = (cls == 0) ? w3 : (cls == 1) ? w4 : w5;
            v = w[(f * DD + d) * K + s];
        }
    }
    W5[idx] = f2bf(v);
}

// ---- ragged segment-mean -> bf16 hist[b][52][320], vectorized ushort4 gather ----
#define PCHUNK 32
__global__ __launch_bounds__(512, 1) void gather_kernel(
    const int* __restrict__ hist_tokens, const int* __restrict__ seg,
    const unsigned short* __restrict__ embb, unsigned short* __restrict__ histb)
{
    __shared__ int tokoff[PCHUNK * LL];
    const int b = blockIdx.x, tid = threadIdx.x;
    const int lo = lower_bound_i(seg, NP, b);
    const int hi = lower_bound_i(seg, NP, b + 1);
    const float inv = 1.0f / fmaxf((float)(hi - lo), 1.0f);

    // slots: idx = tid + 512*j over [0, 3750): t = idx/75, dquad = idx%75
    int toff[8], doff[8];
    #pragma unroll
    for (int j = 0; j < 8; ++j) {
        int idx = tid + 512 * j;
        if (idx < 3750) { toff[j] = idx / 75; doff[j] = (idx % 75) * 4; }
        else            { toff[j] = 0;        doff[j] = 0; }
    }
    const bool has8 = (tid < 166);

    float4 acc[8];
    #pragma unroll
    for (int j = 0; j < 8; ++j) acc[j] = make_float4(0.f, 0.f, 0.f, 0.f);

    for (int p0 = lo; p0 < hi; p0 += PCHUNK) {
        const int pc = min(PCHUNK, hi - p0);
        __syncthreads();
        for (int j = tid; j < pc * LL; j += 512)
            tokoff[j] = hist_tokens[p0 * LL + j] * DD;
        __syncthreads();
        for (int pp = 0; pp < pc; ++pp) {
            const int* tr = tokoff + pp * LL;
            #pragma unroll
            for (int j = 0; j < 7; ++j) {
                const ushort4 v = *(const ushort4*)(embb + tr[toff[j]] + doff[j]);
                acc[j].x += bf2f(v.x); acc[j].y += bf2f(v.y);
                acc[j].z += bf2f(v.z); acc[j].w += bf2f(v.w);
            }
            if (has8) {
                const ushort4 v = *(const ushort4*)(embb + tr[toff[7]] + doff[7]);
                acc[7].x += bf2f(v.x); acc[7].y += bf2f(v.y);
                acc[7].z += bf2f(v.z); acc[7].w += bf2f(v.w);
            }
        }
    }

    unsigned short* hb = histb + (size_t)b * TP * DP;
    #pragma unroll
    for (int j = 0; j < 8; ++j) {
        if (j < 7 || has8) {
            ushort4 o;
            o.x = f2bf(acc[j].x * inv); o.y = f2bf(acc[j].y * inv);
            o.z = f2bf(acc[j].z * inv); o.w = f2bf(acc[j].w * inv);
            *(ushort4*)(hb + toff[j] * DP + doff[j]) = o;
        }
    }
    // zero pads: t in {50,51} x d[0,320)  +  t<50 x d[300,320)
    for (int i = tid; i < 640 + 1000; i += 512) {
        int t, d;
        if (i < 640) { t = 50 + i / 320; d = i % 320; }
        else         { int j = i - 640; t = j / 20; d = 300 + j % 20; }
        hb[t * DP + d] = 0;
    }
}

// ---- conv: 4 users/block, A+B staged in LDS, 8 waves = (user, n-half) ----
__global__ __launch_bounds__(512, 1) void conv_kernel(
    const unsigned short* __restrict__ histb, const unsigned short* __restrict__ W5,
    const float* __restrict__ bias_all,
    const float* __restrict__ hist_w, const float* __restrict__ hist_b,
    float* __restrict__ out)
{
    __shared__ __align__(16) unsigned short sA[UPB * 52 * 40];  // 16,640 B (rows padded 32->40)
    __shared__ __align__(16) unsigned short sB[320 * 40];       // 25,600 B

    const int b = blockIdx.x, tid = threadIdx.x;
    const int wave = tid >> 6, lane = tid & 63;
    const int col = lane & 15, quad = lane >> 4;
    const int u = wave >> 1, h = wave & 1;

    v4f acc[3][10];
    #pragma unroll
    for (int m = 0; m < 3; ++m)
        #pragma unroll
        for (int n = 0; n < 10; ++n)
            acc[m][n] = (v4f){0.f, 0.f, 0.f, 0.f};

    const unsigned short* hbase = histb + (size_t)(b * UPB) * TP * DP;

    for (int kt = 0; kt < 10; ++kt) {
        __syncthreads();                       // prev iter's sA reads done
        for (int idx = tid; idx < UPB * 52 * 4; idx += 512) {
            int uu = idx / 208, r = idx % 208, row = r >> 2, ch = r & 3;
            *(v8s*)(sA + (uu * 52 + row) * 40 + ch * 8) =
                *(const v8s*)(hbase + (size_t)uu * TP * DP + row * DP + kt * 32 + ch * 8);
        }
        for (int s = 0; s < 5; ++s) {
            __syncthreads();                   // prev sB reads done / sA staged
            for (int idx = tid; idx < 1280; idx += 512) {
                int row = idx >> 2, ch = idx & 3;
                *(v8s*)(sB + row * 40 + ch * 8) =
                    *(const v8s*)(W5 + ((size_t)(s * NPADF + row)) * DP + kt * 32 + ch * 8);
            }
            __syncthreads();                   // sB staged
            v8s a[3];
            #pragma unroll
            for (int m = 0; m < 3; ++m)
                a[m] = *(const v8s*)(sA + (u * 52 + m * 16 + col + s) * 40 + quad * 8);
            #pragma unroll
            for (int n = 0; n < 10; ++n) {
                const v8s bf = *(const v8s*)(sB + ((h * 10 + n) * 16 + col) * 40 + quad * 8);
                #pragma unroll
                for (int m = 0; m < 3; ++m)
                    acc[m][n] = __builtin_amdgcn_mfma_f32_16x16x32_bf16(a[m], bf, acc[m][n], 0, 0, 0);
            }
        }
    }

    // maxpool + bias + relu -> fpool (alias over sB, safe after sync)
    __syncthreads();
    float* fpool = (float*)sB;                 // [UPB][320]
    #pragma unroll
    for (int n = 0; n < 10; ++n) {
        const int nf = (h * 10 + n) * 16 + col;
        const int Tout = 48 - nf / 100;        // 48/47/46 (pad filters unused)
        float mx = -1e30f;
        #pragma unroll
        for (int m = 0; m < 3; ++m)
            #pragma unroll
            for (int r = 0; r < 4; ++r) {
                int t = m * 16 + quad * 4 + r;
                if (t < Tout) mx = fmaxf(mx, acc[m][n][r]);
            }
        mx = fmaxf(mx, __shfl_xor(mx, 16, 64));
        mx = fmaxf(mx, __shfl_xor(mx, 32, 64));
        if (quad == 0 && nf < NTOT)
            fpool[u * 320 + nf] = fmaxf(0.f, mx + bias_all[nf]);
    }
    __syncthreads();

    // rec = fpool @ hist_w.T + hist_b
    if (tid < UPB * 64) {
        const int uu = tid >> 6, o = tid & 63;
        const float4* fw = (const float4*)(hist_w + o * NTOT);
        const float4* fp = (const float4*)(fpool + uu * 320);
        float s = 0.f;
        #pragma unroll
        for (int q = 0; q < NTOT / 4; ++q) {
            float4 aa = fp[q], ww = fw[q];
            s += aa.x * ww.x + aa.y * ww.y + aa.z * ww.z + aa.w * ww.w;
        }
        out[(b * UPB + uu) * 64 + o] = s + hist_b[o];
    }
}

// ---- fc: 16 users per block; w1 traffic amortized 16x ----
__global__ __launch_bounds__(512, 1) void fc_kernel(
    const float* __restrict__ x, const int* __restrict__ rootindex,
    const float* __restrict__ w1, const float* __restrict__ b1,
    const float* __restrict__ w2, const float* __restrict__ b2,
    float* __restrict__ out)
{
    __shared__ __align__(16) float xr[16 * INFEAT];   // 49,152 B
    __shared__ __align__(16) float hbuf[16 * HID2];   //  8,192 B
    const int b = blockIdx.x, tid = threadIdx.x;

    // stage 16 root rows (float4)
    for (int c = tid; c < 16 * (INFEAT / 4); c += 512) {
        int uu = c / (INFEAT / 4), q = c % (INFEAT / 4);
        int root = rootindex[b * 16 + uu];
        ((float4*)xr)[c] = ((const float4*)(x + (size_t)root * INFEAT))[q];
    }
    __syncthreads();

    // phase 1: h[u][o] = relu(x[u] . w1[o] + b1[o]); thread = (u=tid>>5, og=tid&31 -> 4 o)
    {
        const int uu = tid >> 5, og = tid & 31;
        float a0 = 0.f, a1 = 0.f, a2 = 0.f, a3 = 0.f;
        const float4* xv = (const float4*)(xr + uu * INFEAT);
        const float4* w0 = (const float4*)(w1 + (og * 4 + 0) * INFEAT);
        const float4* w1r = (const float4*)(w1 + (og * 4 + 1) * INFEAT);
        const float4* w2r = (const float4*)(w1 + (og * 4 + 2) * INFEAT);
        const float4* w3r = (const float4*)(w1 + (og * 4 + 3) * INFEAT);
        for (int k = 0; k < INFEAT / 4; ++k) {
            float4 xa = xv[k];
            float4 v0 = w0[k], v1 = w1r[k], v2 = w2r[k], v3 = w3r[k];
            a0 += xa.x * v0.x + xa.y * v0.y + xa.z * v0.z + xa.w * v0.w;
            a1 += xa.x * v1.x + xa.y * v1.y + xa.z * v1.z + xa.w * v1.w;
            a2 += xa.x * v2.x + xa.y * v2.y + xa.z * v2.z + xa.w * v2.w;
            a3 += xa.x * v3.x + xa.y * v3.y + xa.z * v3.z + xa.w * v3.w;
        }
        hbuf[uu * HID2 + og * 4 + 0] = fmaxf(a0 + b1[og * 4 + 0], 0.f);
        hbuf[uu * HID2 + og * 4 + 1] = fmaxf(a1 + b1[og * 4 + 1], 0.f);
        hbuf[uu * HID2 + og * 4 + 2] = fmaxf(a2 + b1[og * 4 + 2], 0.f);
        hbuf[uu * HID2 + og * 4 + 3] = fmaxf(a3 + b1[og * 4 + 3], 0.f);
    }
    __syncthreads();

    // phase 2: out[u][o] += h[u] . w2[o] + b2[o]; thread = (u=tid>>5, og=tid&31 -> 2 o)
    {
        const int uu = tid >> 5, og = tid & 31;
        const float4* hv = (const float4*)(hbuf + uu * HID2);
        #pragma unroll
        for (int i = 0; i < 2; ++i) {
            const int o = og * 2 + i;
            const float4* wv = (const float4*)(w2 + o * HID2);
            float s = 0.f;
            #pragma unroll
            for (int k = 0; k < HID2 / 4; ++k) {
                float4 ha = hv[k], wa = wv[k];
                s += ha.x * wa.x + ha.y * wa.y + ha.z * wa.z + ha.w * wa.w;
            }
            out[(b * 16 + uu) * 64 + o] += s + b2[o];
        }
    }
}

extern "C" void kernel_launch(void* const* d_in, const int* in_sizes, int n_in,
                              void* d_out, int out_size, void* d_ws, size_t ws_size,
                              hipStream_t stream) {
    const float* x        = (const float*)d_in[0];
    const int*   rootidx  = (const int*)d_in[1];
    const int*   hist_tok = (const int*)d_in[2];
    const int*   seg      = (const int*)d_in[3];
    const float* emb      = (const float*)d_in[4];
    const float* w3       = (const float*)d_in[5];
    const float* cb3      = (const float*)d_in[6];
    const float* w4       = (const float*)d_in[7];
    const float* cb4      = (const float*)d_in[8];
    const float* w5       = (const float*)d_in[9];
    const float* cb5      = (const float*)d_in[10];
    const float* hist_w   = (const float*)d_in[11];
    const float* hist_b   = (const float*)d_in[12];
    const float* fw1      = (const float*)d_in[13];
    const float* fb1      = (const float*)d_in[14];
    const float* fw2      = (const float*)d_in[15];
    const float* fb2      = (const float*)d_in[16];
    float* out = (float*)d_out;

    // workspace layout (bytes)
    char* ws = (char*)d_ws;
    unsigned short* emb_bf  = (unsigned short*)(ws);                    // 30,000,000 B
    unsigned short* hist_bf = (unsigned short*)(ws + 30000000);         // 68,157,440 B
    unsigned short* W5      = (unsigned short*)(ws + 98157440);         //  1,024,000 B
    float*          bias_all= (float*)(ws + 99181440);                  //      1,280 B

    emb_cvt<<<(50000 * DD / 4 + 255) / 256, 256, 0, stream>>>(emb, emb_bf, 50000 * DD / 4);
    prep_w<<<(5 * NPADF * DP + 255) / 256, 256, 0, stream>>>(w3, w4, w5, cb3, cb4, cb5, W5, bias_all);
    gather_kernel<<<NB, 512, 0, stream>>>(hist_tok, seg, emb_bf, hist_bf);
    conv_kernel<<<NB / UPB, 512, 0, stream>>>(hist_bf, W5, bias_all, hist_w, hist_b, out);
    fc_kernel<<<NB / 16, 512, 0, stream>>>(x, rootidx, fw1, fb1, fw2, fb2, out);
}

// Round 4
// 410.146 us; speedup vs baseline: 6.8824x; 1.4032x over previous
//
#include <hip/hip_runtime.h>

// Problem constants
#define NB    2048     // users / segments
#define NP    16384    // posts
#define LL    50       // tokens per post
#define DD    300      // embedding dim
#define DP    320      // d padded to multiple of 32 (MFMA K tiles)
#define TP    52       // t rows incl. zero pad (48 outputs + 4 shift overhang)
#define NTOT  300      // total filters (100 per conv)
#define NPADF 320      // filters padded to 20 N-tiles of 16
#define INFEAT 768
#define HID2  128
#define UPB   4        // users per conv block
#define FCM   16       // users per fc block

typedef short v8s __attribute__((ext_vector_type(8)));
typedef float v4f __attribute__((ext_vector_type(4)));

__device__ __forceinline__ unsigned short f2bf(float f) {
    union { float f; unsigned u; } v; v.f = f;
    return (unsigned short)((v.u + 0x7FFF + ((v.u >> 16) & 1)) >> 16);  // RNE
}
__device__ __forceinline__ float bf2f(unsigned short u) {
    union { unsigned u; float f; } v; v.u = ((unsigned)u) << 16; return v.f;
}
__device__ __forceinline__ int lower_bound_i(const int* __restrict__ a, int n, int v) {
    int lo = 0, hi = n;
    while (lo < hi) { int mid = (lo + hi) >> 1; if (a[mid] < v) lo = mid + 1; else hi = mid; }
    return lo;
}

// ---- generic fp32 -> bf16 (used for emb table and fc_w1) ----
__global__ void emb_cvt(const float* __restrict__ in, unsigned short* __restrict__ out, int n4) {
    int i = blockIdx.x * blockDim.x + threadIdx.x;
    if (i >= n4) return;
    float4 v = ((const float4*)in)[i];
    ushort4 o; o.x = f2bf(v.x); o.y = f2bf(v.y); o.z = f2bf(v.z); o.w = f2bf(v.w);
    ((ushort4*)out)[i] = o;
}

// ---- conv weights -> bf16 W5[shift(5)][nf(320)][d(320)] + bias_all[320] ----
__global__ void prep_w(const float* __restrict__ w3, const float* __restrict__ w4,
                       const float* __restrict__ w5,
                       const float* __restrict__ b3, const float* __restrict__ b4,
                       const float* __restrict__ b5,
                       unsigned short* __restrict__ W5, float* __restrict__ bias_all) {
    int idx = blockIdx.x * blockDim.x + threadIdx.x;
    if (idx < NPADF) {
        float bv = 0.f;
        if (idx < 100) bv = b3[idx];
        else if (idx < 200) bv = b4[idx - 100];
        else if (idx < 300) bv = b5[idx - 200];
        bias_all[idx] = bv;
    }
    if (idx >= 5 * NPADF * DP) return;
    int d  = idx % DP;
    int r  = idx / DP;
    int nf = r % NPADF;
    int s  = r / NPADF;
    float v = 0.f;
    if (nf < NTOT && d < DD) {
        int cls = nf / 100, f = nf % 100, K = cls + 3;
        if (s < K) {
            const float* w = (cls == 0) ? w3 : (cls == 1) ? w4 : w5;
            v = w[(f * DD + d) * K + s];
        }
    }
    W5[idx] = f2bf(v);
}

// ---- ragged segment-mean -> bf16 hist[b][52][320], vectorized ushort4 gather ----
#define PCHUNK 32
__global__ __launch_bounds__(512, 1) void gather_kernel(
    const int* __restrict__ hist_tokens, const int* __restrict__ seg,
    const unsigned short* __restrict__ embb, unsigned short* __restrict__ histb)
{
    __shared__ int tokoff[PCHUNK * LL];
    const int b = blockIdx.x, tid = threadIdx.x;
    const int lo = lower_bound_i(seg, NP, b);
    const int hi = lower_bound_i(seg, NP, b + 1);
    const float inv = 1.0f / fmaxf((float)(hi - lo), 1.0f);

    // slots: idx = tid + 512*j over [0, 3750): t = idx/75, dquad = idx%75
    int toff[8], doff[8];
    #pragma unroll
    for (int j = 0; j < 8; ++j) {
        int idx = tid + 512 * j;
        if (idx < 3750) { toff[j] = idx / 75; doff[j] = (idx % 75) * 4; }
        else            { toff[j] = 0;        doff[j] = 0; }
    }
    const bool has8 = (tid < 166);

    float4 acc[8];
    #pragma unroll
    for (int j = 0; j < 8; ++j) acc[j] = make_float4(0.f, 0.f, 0.f, 0.f);

    for (int p0 = lo; p0 < hi; p0 += PCHUNK) {
        const int pc = min(PCHUNK, hi - p0);
        __syncthreads();
        for (int j = tid; j < pc * LL; j += 512)
            tokoff[j] = hist_tokens[p0 * LL + j] * DD;
        __syncthreads();
        for (int pp = 0; pp < pc; ++pp) {
            const int* tr = tokoff + pp * LL;
            #pragma unroll
            for (int j = 0; j < 7; ++j) {
                const ushort4 v = *(const ushort4*)(embb + tr[toff[j]] + doff[j]);
                acc[j].x += bf2f(v.x); acc[j].y += bf2f(v.y);
                acc[j].z += bf2f(v.z); acc[j].w += bf2f(v.w);
            }
            if (has8) {
                const ushort4 v = *(const ushort4*)(embb + tr[toff[7]] + doff[7]);
                acc[7].x += bf2f(v.x); acc[7].y += bf2f(v.y);
                acc[7].z += bf2f(v.z); acc[7].w += bf2f(v.w);
            }
        }
    }

    unsigned short* hb = histb + (size_t)b * TP * DP;
    #pragma unroll
    for (int j = 0; j < 8; ++j) {
        if (j < 7 || has8) {
            ushort4 o;
            o.x = f2bf(acc[j].x * inv); o.y = f2bf(acc[j].y * inv);
            o.z = f2bf(acc[j].z * inv); o.w = f2bf(acc[j].w * inv);
            *(ushort4*)(hb + toff[j] * DP + doff[j]) = o;
        }
    }
    // zero pads: t in {50,51} x d[0,320)  +  t<50 x d[300,320)
    for (int i = tid; i < 640 + 1000; i += 512) {
        int t, d;
        if (i < 640) { t = 50 + i / 320; d = i % 320; }
        else         { int j = i - 640; t = j / 20; d = 300 + j % 20; }
        hb[t * DP + d] = 0;
    }
}

// ---- conv: 4 users/block, A+B staged in LDS, 8 waves = (user, n-half) ----
__global__ __launch_bounds__(512, 1) void conv_kernel(
    const unsigned short* __restrict__ histb, const unsigned short* __restrict__ W5,
    const float* __restrict__ bias_all,
    const float* __restrict__ hist_w, const float* __restrict__ hist_b,
    float* __restrict__ out)
{
    __shared__ __align__(16) unsigned short sA[UPB * 52 * 40];  // 16,640 B (rows padded 32->40)
    __shared__ __align__(16) unsigned short sB[320 * 40];       // 25,600 B

    const int b = blockIdx.x, tid = threadIdx.x;
    const int wave = tid >> 6, lane = tid & 63;
    const int col = lane & 15, quad = lane >> 4;
    const int u = wave >> 1, h = wave & 1;

    v4f acc[3][10];
    #pragma unroll
    for (int m = 0; m < 3; ++m)
        #pragma unroll
        for (int n = 0; n < 10; ++n)
            acc[m][n] = (v4f){0.f, 0.f, 0.f, 0.f};

    const unsigned short* hbase = histb + (size_t)(b * UPB) * TP * DP;

    for (int kt = 0; kt < 10; ++kt) {
        __syncthreads();                       // prev iter's sA reads done
        for (int idx = tid; idx < UPB * 52 * 4; idx += 512) {
            int uu = idx / 208, r = idx % 208, row = r >> 2, ch = r & 3;
            *(v8s*)(sA + (uu * 52 + row) * 40 + ch * 8) =
                *(const v8s*)(hbase + (size_t)uu * TP * DP + row * DP + kt * 32 + ch * 8);
        }
        for (int s = 0; s < 5; ++s) {
            __syncthreads();                   // prev sB reads done / sA staged
            for (int idx = tid; idx < 1280; idx += 512) {
                int row = idx >> 2, ch = idx & 3;
                *(v8s*)(sB + row * 40 + ch * 8) =
                    *(const v8s*)(W5 + ((size_t)(s * NPADF + row)) * DP + kt * 32 + ch * 8);
            }
            __syncthreads();                   // sB staged
            v8s a[3];
            #pragma unroll
            for (int m = 0; m < 3; ++m)
                a[m] = *(const v8s*)(sA + (u * 52 + m * 16 + col + s) * 40 + quad * 8);
            #pragma unroll
            for (int n = 0; n < 10; ++n) {
                const v8s bf = *(const v8s*)(sB + ((h * 10 + n) * 16 + col) * 40 + quad * 8);
                #pragma unroll
                for (int m = 0; m < 3; ++m)
                    acc[m][n] = __builtin_amdgcn_mfma_f32_16x16x32_bf16(a[m], bf, acc[m][n], 0, 0, 0);
            }
        }
    }

    // maxpool + bias + relu -> fpool (alias over sB, safe after sync)
    __syncthreads();
    float* fpool = (float*)sB;                 // [UPB][320]
    #pragma unroll
    for (int n = 0; n < 10; ++n) {
        const int nf = (h * 10 + n) * 16 + col;
        const int Tout = 48 - nf / 100;        // 48/47/46 (pad filters unused)
        float mx = -1e30f;
        #pragma unroll
        for (int m = 0; m < 3; ++m)
            #pragma unroll
            for (int r = 0; r < 4; ++r) {
                int t = m * 16 + quad * 4 + r;
                if (t < Tout) mx = fmaxf(mx, acc[m][n][r]);
            }
        mx = fmaxf(mx, __shfl_xor(mx, 16, 64));
        mx = fmaxf(mx, __shfl_xor(mx, 32, 64));
        if (quad == 0 && nf < NTOT)
            fpool[u * 320 + nf] = fmaxf(0.f, mx + bias_all[nf]);
    }
    __syncthreads();

    // rec = fpool @ hist_w.T + hist_b
    if (tid < UPB * 64) {
        const int uu = tid >> 6, o = tid & 63;
        const float4* fw = (const float4*)(hist_w + o * NTOT);
        const float4* fp = (const float4*)(fpool + uu * 320);
        float s = 0.f;
        #pragma unroll
        for (int q = 0; q < NTOT / 4; ++q) {
            float4 aa = fp[q], ww = fw[q];
            s += aa.x * ww.x + aa.y * ww.y + aa.z * ww.z + aa.w * ww.w;
        }
        out[(b * UPB + uu) * 64 + o] = s + hist_b[o];
    }
}

// ---- fc via MFMA: h = relu(x[root] @ w1b.T + b1) ; out += h @ w2.T + b2 ----
// 128 blocks x 16 users. A (x rows) staged fp32->bf16 in LDS per K-chunk of 64.
// B-frags read direct from bf16 w1b (L2-resident). Phase 2 VALU vs LDS-staged w2.
__global__ __launch_bounds__(256, 1) void fc_mfma(
    const float* __restrict__ x, const int* __restrict__ rootindex,
    const unsigned short* __restrict__ w1b, const float* __restrict__ b1,
    const float* __restrict__ w2, const float* __restrict__ b2,
    float* __restrict__ out)
{
    __shared__ __align__(16) unsigned short sA[FCM * 72];   // 16 rows x 64k (pad 72)
    __shared__ __align__(16) float hl[FCM * 132];           // h tile, stride 132
    __shared__ __align__(16) float w2l[64 * 129];           // w2 staged, stride 129
    __shared__ int roots[FCM];

    const int b = blockIdx.x, tid = threadIdx.x;
    if (tid < FCM) roots[tid] = rootindex[b * FCM + tid];
    // stage w2 (64x128) with padded stride
    for (int i = tid; i < 64 * HID2; i += 256)
        w2l[(i >> 7) * 129 + (i & 127)] = w2[i];
    __syncthreads();

    const int wave = tid >> 6, lane = tid & 63;
    const int col = lane & 15, quad = lane >> 4;

    v4f acc[2];
    acc[0] = (v4f){0.f, 0.f, 0.f, 0.f};
    acc[1] = (v4f){0.f, 0.f, 0.f, 0.f};

    const int r_st = tid >> 4, q_st = tid & 15;   // staging: row, float4 idx in 64-k chunk

    for (int kt = 0; kt < 12; ++kt) {
        __syncthreads();                          // prev sA reads done
        float4 v = *(const float4*)(x + (size_t)roots[r_st] * INFEAT + kt * 64 + q_st * 4);
        ushort4 o; o.x = f2bf(v.x); o.y = f2bf(v.y); o.z = f2bf(v.z); o.w = f2bf(v.w);
        *(ushort4*)(sA + r_st * 72 + q_st * 4) = o;
        __syncthreads();                          // sA staged
        #pragma unroll
        for (int kc = 0; kc < 2; ++kc) {
            const v8s a = *(const v8s*)(sA + col * 72 + kc * 32 + quad * 8);
            #pragma unroll
            for (int n = 0; n < 2; ++n) {
                const int nf = (wave * 2 + n) * 16 + col;
                const v8s bf = *(const v8s*)(w1b + (size_t)nf * INFEAT + kt * 64 + kc * 32 + quad * 8);
                acc[n] = __builtin_amdgcn_mfma_f32_16x16x32_bf16(a, bf, acc[n], 0, 0, 0);
            }
        }
    }

    // h tile -> LDS with bias+relu.  C layout: m = quad*4+r, n = (wave*2+nt)*16 + col
    #pragma unroll
    for (int nt = 0; nt < 2; ++nt) {
        const int n = (wave * 2 + nt) * 16 + col;
        const float bv = b1[n];
        #pragma unroll
        for (int r = 0; r < 4; ++r)
            hl[(quad * 4 + r) * 132 + n] = fmaxf(acc[nt][r] + bv, 0.f);
    }
    __syncthreads();

    // phase 2: out[u][o] += hl[u] . w2l[o] + b2[o]
    {
        const int o = tid & 63, ug = tid >> 6;
        const float b2v = b2[o];
        const float* wrow = w2l + o * 129;
        #pragma unroll
        for (int i = 0; i < 4; ++i) {
            const int u = ug * 4 + i;
            const float* hrow = hl + u * 132;
            float s = 0.f;
            #pragma unroll 16
            for (int k = 0; k < HID2; ++k) s += hrow[k] * wrow[k];
            out[(b * FCM + u) * 64 + o] += s + b2v;
        }
    }
}

extern "C" void kernel_launch(void* const* d_in, const int* in_sizes, int n_in,
                              void* d_out, int out_size, void* d_ws, size_t ws_size,
                              hipStream_t stream) {
    const float* x        = (const float*)d_in[0];
    const int*   rootidx  = (const int*)d_in[1];
    const int*   hist_tok = (const int*)d_in[2];
    const int*   seg      = (const int*)d_in[3];
    const float* emb      = (const float*)d_in[4];
    const float* w3       = (const float*)d_in[5];
    const float* cb3      = (const float*)d_in[6];
    const float* w4       = (const float*)d_in[7];
    const float* cb4      = (const float*)d_in[8];
    const float* w5       = (const float*)d_in[9];
    const float* cb5      = (const float*)d_in[10];
    const float* hist_w   = (const float*)d_in[11];
    const float* hist_b   = (const float*)d_in[12];
    const float* fw1      = (const float*)d_in[13];
    const float* fb1      = (const float*)d_in[14];
    const float* fw2      = (const float*)d_in[15];
    const float* fb2      = (const float*)d_in[16];
    float* out = (float*)d_out;

    // workspace layout (bytes)
    char* ws = (char*)d_ws;
    unsigned short* emb_bf  = (unsigned short*)(ws);                    // 30,000,000 B
    unsigned short* hist_bf = (unsigned short*)(ws + 30000000);         // 68,157,440 B
    unsigned short* W5      = (unsigned short*)(ws + 98157440);         //  1,024,000 B
    float*          bias_all= (float*)(ws + 99181440);                  //      1,280 B
    unsigned short* w1b     = (unsigned short*)(ws + 99182720);         //    196,608 B

    emb_cvt<<<(50000 * DD / 4 + 255) / 256, 256, 0, stream>>>(emb, emb_bf, 50000 * DD / 4);
    emb_cvt<<<(HID2 * INFEAT / 4 + 255) / 256, 256, 0, stream>>>(fw1, w1b, HID2 * INFEAT / 4);
    prep_w<<<(5 * NPADF * DP + 255) / 256, 256, 0, stream>>>(w3, w4, w5, cb3, cb4, cb5, W5, bias_all);
    gather_kernel<<<NB, 512, 0, stream>>>(hist_tok, seg, emb_bf, hist_bf);
    conv_kernel<<<NB / UPB, 512, 0, stream>>>(hist_bf, W5, bias_all, hist_w, hist_b, out);
    fc_mfma<<<NB / FCM, 256, 0, stream>>>(x, rootidx, w1b, fb1, fw2, fb2, out);
}